// Round 11
// baseline (76.407 us; speedup 1.0000x reference)
//
#include <hip/hip_runtime.h>
#include <hip/hip_bf16.h>
#include <hip/hip_fp16.h>

#define A_NUM 128
#define U_NUM 8
#define ANT 64
#define D2 64
#define H_DIM 256
#define NUE 1024
#define E_INT 131072

typedef __attribute__((ext_vector_type(8))) short bf16x8_t;
typedef __attribute__((ext_vector_type(4))) short bf16x4_t;
typedef __attribute__((ext_vector_type(4))) float f32x4_t;

// round-to-nearest-even f32 -> bf16
static __device__ inline unsigned short f2bf(float x) {
    unsigned int u = __float_as_uint(x);
    unsigned int r = (u + 0x7fffu + ((u >> 16) & 1u)) >> 16;
    return (unsigned short)r;
}
static __device__ inline unsigned int pack2(float a, float b) {
    return (unsigned int)f2bf(a) | ((unsigned int)f2bf(b) << 16);
}
static __device__ inline unsigned int packh2(float a, float b) {
    return (unsigned int)__half_as_ushort(__float2half(a)) |
           ((unsigned int)__half_as_ushort(__float2half(b)) << 16);
}
// relu + cvt to l2 B-frag (k = lk*4 + i matches rows r of l1T output)
static __device__ inline bf16x4_t relu_cvt4(f32x4_t v) {
    float t0 = v[0] > 0.f ? v[0] : 0.f;
    float t1 = v[1] > 0.f ? v[1] : 0.f;
    float t2 = v[2] > 0.f ? v[2] : 0.f;
    float t3 = v[3] > 0.f ? v[3] : 0.f;
    union { unsigned int u[2]; bf16x4_t s; } r;
    r.u[0] = pack2(t0, t1);
    r.u[1] = pack2(t2, t3);
    return r.s;
}

// ---------------------------------------------------------------------------
// Kernel A: prep. blocks 0..127: Sa[a,h]. blocks 128..135: fragment-order
// bf16 weight packs WpF (l1 A-frags) / W2F (l2 A-frags, K=16 layout).
// blocks 136..167: f32 transposes W1aT[256][208] (pad), W1bT[128][256].
// ---------------------------------------------------------------------------
__global__ void prep_kernel(const float* __restrict__ pv_re, const float* __restrict__ pv_im,
                            const float* __restrict__ W2a, const float* __restrict__ b2a,
                            const float* __restrict__ W2b,
                            const float* __restrict__ W1a, const float* __restrict__ W1b,
                            float* __restrict__ Sa, unsigned short* __restrict__ WpF,
                            unsigned short* __restrict__ W2F,
                            float* __restrict__ W1aT, float* __restrict__ W1bT) {
    int bid = blockIdx.x, t = threadIdx.x;
    if (bid < A_NUM) {
        __shared__ float sre[ANT], sim[ANT];
        if (t < ANT) {
            float s = 0.f;
            for (int u = 0; u < U_NUM; ++u) s += pv_re[bid * 512 + u * 64 + t];
            sre[t] = s;
        } else if (t < 2 * ANT) {
            int ant = t - ANT;
            float s = 0.f;
            for (int u = 0; u < U_NUM; ++u) s += pv_im[bid * 512 + u * 64 + ant];
            sim[ant] = s;
        }
        __syncthreads();
        float a0 = 0.f, a1 = 0.f, a2 = 0.f, a3 = 0.f;
        for (int ant = 0; ant < ANT; ant += 2) {
            a0 += sre[ant] * W2a[(64 + ant) * H_DIM + t];
            a1 += sim[ant] * W2a[(192 + ant) * H_DIM + t];
            a2 += sre[ant + 1] * W2a[(64 + ant + 1) * H_DIM + t];
            a3 += sim[ant + 1] * W2a[(192 + ant + 1) * H_DIM + t];
        }
        Sa[bid * H_DIM + t] = b2a[t] + ((a0 + a2) + (a1 + a3));
    } else if (bid < 136) {
        int base = (bid - A_NUM) * 256 + t;
        for (int f = base; f < 32768 + 16384; f += 8 * 256) {
            if (f < 32768) {  // WpF (l1 A-frags, K=32 layout)
                int i = f & 7, lml = (f >> 3) & 15, lkl = (f >> 7) & 3;
                int kc = (f >> 9) & 3, ht8 = (f >> 11) & 7, hh = (f >> 14) & 1;
                int h = hh * 128 + ht8 * 16 + lml;
                int k = kc * 32 + lkl * 8 + i;
                int row = (k < 64) ? k : (k + 64);
                WpF[f] = f2bf(W2a[row * H_DIM + h]);
            } else {          // W2F (l2 A-frags, K=16 layout)
                int f2 = f - 32768;
                int i = f2 & 3, ll = (f2 >> 2) & 63;
                int dt = (f2 >> 8) & 3, ht8 = (f2 >> 10) & 7, hh = (f2 >> 13) & 1;
                int d = dt * 16 + (ll & 15);
                int k = hh * 128 + ht8 * 16 + (ll >> 4) * 4 + i;
                W2F[f2] = f2bf(W2b[k * D2 + d]);
            }
        }
    } else {
        for (int i = (bid - 136) * 256 + t; i < 53248 + 32768; i += 32 * 256) {
            if (i < 53248) {
                int k = i >> 8, h = i & 255;
                W1aT[h * 208 + k] = (k < 193) ? W1a[k * 256 + h] : 0.f;
            } else {
                int i2 = i - 53248;
                int k = i2 >> 7, c = i2 & 127;
                W1bT[c * 256 + k] = W1b[k * 128 + c];
            }
        }
    }
}

// ---------------------------------------------------------------------------
// Kernel B: big edge MLP, transpose-free, weight-amortized. Grid 512 =
// 16 jt(64j) x 2 hh x 16 ac, 256 thr (4 waves), exactly 2 blocks/CU.
// Wave hw: 32h x 64j (j/wave doubled vs R9 -> weight LDS re-reads per j
// halved). l1 swapped (D1T = Wp x F^T) feeds l2 16x16x16 B-frags directly
// in registers. hw k-split partials folded via the dead F buffer.
// LDS 65KB; single F buffer, 2 barriers/iter.
// ---------------------------------------------------------------------------
__global__ __launch_bounds__(256) void mlp2_kernel(
        const float* __restrict__ plre, const float* __restrict__ plim,
        const float* __restrict__ Sa, const unsigned short* __restrict__ WpF,
        const unsigned short* __restrict__ W2F, float* __restrict__ partial,
        unsigned short* __restrict__ Pws) {
    __shared__ __attribute__((aligned(16))) unsigned short Wl[16384];   // 32KB
    __shared__ __attribute__((aligned(16))) unsigned short W2l[8192];   // 16KB
    __shared__ __attribute__((aligned(16))) unsigned short Fbuf[8704];  // [64 j][136 k] 17KB
    int bid = blockIdx.x;
    int ac = bid >> 5, hh = (bid >> 4) & 1, jtile = bid & 15;
    int j0 = jtile * 64, a0 = ac * 8;
    int t = threadIdx.x, l = t & 63, lm = l & 15, lk = l >> 4;
    int hw = t >> 6;  // wave = h-slice

    // ---- stage this hh-half's weights into LDS (once) ----
    {
        const uint4* sW = reinterpret_cast<const uint4*>(WpF + hh * 16384);
        const uint4* sW2 = reinterpret_cast<const uint4*>(W2F + hh * 8192);
        uint4* dW = reinterpret_cast<uint4*>(Wl);
        uint4* dW2 = reinterpret_cast<uint4*>(W2l);
        for (int q = t; q < 3072; q += 256) {
            if (q < 2048) dW[q] = sW[q];
            else dW2[q - 2048] = sW2[q - 2048];
        }
    }

    // ---- staging identity: thread t -> (row r = t>>2, seg = t&3) ----
    // seg 0,1 = re halves (32 cols each); seg 2,3 = im halves.
    int rr = t >> 2, seg = t & 3;
    const float* sb = (seg < 2) ? plre : plim;
    int soff = (j0 + rr) * 64 + (seg & 1) * 32;
    int fw = rr * 136 + ((seg < 2) ? 0 : 64) + (seg & 1) * 32;

    f32x4_t acc2[4][4];  // [dt][jf]
#pragma unroll
    for (int dt = 0; dt < 4; ++dt)
#pragma unroll
        for (int jf = 0; jf < 4; ++jf) acc2[dt][jf] = (f32x4_t){0.f, 0.f, 0.f, 0.f};

    float4 s[8];
    {   // stage a0 directly
        const float* p = sb + (size_t)a0 * 65536 + soff;
#pragma unroll
        for (int i = 0; i < 8; ++i) s[i] = *reinterpret_cast<const float4*>(p + i * 4);
#pragma unroll
        for (int i = 0; i < 4; ++i)
            *reinterpret_cast<uint4*>(&Fbuf[fw + i * 8]) =
                make_uint4(pack2(s[2 * i].x, s[2 * i].y), pack2(s[2 * i].z, s[2 * i].w),
                           pack2(s[2 * i + 1].x, s[2 * i + 1].y), pack2(s[2 * i + 1].z, s[2 * i + 1].w));
    }
    {   // prefetch a1
        const float* p = sb + (size_t)(a0 + 1) * 65536 + soff;
#pragma unroll
        for (int i = 0; i < 8; ++i) s[i] = *reinterpret_cast<const float4*>(p + i * 4);
    }
    __syncthreads();  // weights + F(a0) visible

    for (int ai = 0; ai < 8; ++ai) {
        int a = a0 + ai;
        // ---- P emit (hh==0): thread (rr, seg): 16 ants at seg*16 ----
        if (hh == 0) {
            uint4 re0 = *reinterpret_cast<const uint4*>(Fbuf + rr * 136 + seg * 16);
            uint4 re1 = *reinterpret_cast<const uint4*>(Fbuf + rr * 136 + seg * 16 + 8);
            uint4 im0 = *reinterpret_cast<const uint4*>(Fbuf + rr * 136 + 64 + seg * 16);
            uint4 im1 = *reinterpret_cast<const uint4*>(Fbuf + rr * 136 + 64 + seg * 16 + 8);
            const unsigned short* pr = (const unsigned short*)&re0;
            const unsigned short* pi = (const unsigned short*)&im0;
            unsigned int pk[8];
#pragma unroll
            for (int i = 0; i < 4; ++i) {
                float a0f = __uint_as_float(((unsigned int)pr[2 * i]) << 16);
                float b0f = __uint_as_float(((unsigned int)pi[2 * i]) << 16);
                float a1f = __uint_as_float(((unsigned int)pr[2 * i + 1]) << 16);
                float b1f = __uint_as_float(((unsigned int)pi[2 * i + 1]) << 16);
                pk[i] = packh2(a0f * a0f + b0f * b0f, a1f * a1f + b1f * b1f);
            }
            pr = (const unsigned short*)&re1;
            pi = (const unsigned short*)&im1;
#pragma unroll
            for (int i = 0; i < 4; ++i) {
                float a0f = __uint_as_float(((unsigned int)pr[2 * i]) << 16);
                float b0f = __uint_as_float(((unsigned int)pi[2 * i]) << 16);
                float a1f = __uint_as_float(((unsigned int)pr[2 * i + 1]) << 16);
                float b1f = __uint_as_float(((unsigned int)pi[2 * i + 1]) << 16);
                pk[4 + i] = packh2(a0f * a0f + b0f * b0f, a1f * a1f + b1f * b1f);
            }
            unsigned short* pd = Pws + (unsigned)(a * 1024 + j0 + rr) * 64 + seg * 16;
            *reinterpret_cast<uint4*>(pd) = make_uint4(pk[0], pk[1], pk[2], pk[3]);
            *reinterpret_cast<uint4*>(pd + 8) = make_uint4(pk[4], pk[5], pk[6], pk[7]);
        }
        // ---- layer 1 (swapped): D1T[h][j], wave tile 32h x 64j ----
        f32x4_t acc1[2][4];  // [ht][jf]
#pragma unroll
        for (int ht = 0; ht < 2; ++ht) {
            f32x4_t sa = *reinterpret_cast<const f32x4_t*>(
                Sa + a * H_DIM + hh * 128 + hw * 32 + ht * 16 + lk * 4);
#pragma unroll
            for (int jf = 0; jf < 4; ++jf) acc1[ht][jf] = sa;
        }
#pragma unroll
        for (int kc = 0; kc < 4; ++kc) {
            bf16x8_t aw0 = *reinterpret_cast<const bf16x8_t*>(
                Wl + (((hw * 2 + 0) * 4 + kc) << 9) + l * 8);
            bf16x8_t aw1 = *reinterpret_cast<const bf16x8_t*>(
                Wl + (((hw * 2 + 1) * 4 + kc) << 9) + l * 8);
#pragma unroll
            for (int jf = 0; jf < 4; ++jf) {
                bf16x8_t bf = *reinterpret_cast<const bf16x8_t*>(
                    Fbuf + (jf * 16 + lm) * 136 + kc * 32 + lk * 8);
                acc1[0][jf] = __builtin_amdgcn_mfma_f32_16x16x32_bf16(aw0, bf, acc1[0][jf], 0, 0, 0);
                acc1[1][jf] = __builtin_amdgcn_mfma_f32_16x16x32_bf16(aw1, bf, acc1[1][jf], 0, 0, 0);
            }
        }
        // ---- layer 2: relu+cvt in-register, 16x16x16 MFMA per ht ----
#pragma unroll
        for (int ht = 0; ht < 2; ++ht) {
            bf16x4_t hl[4];
#pragma unroll
            for (int jf = 0; jf < 4; ++jf) hl[jf] = relu_cvt4(acc1[ht][jf]);
#pragma unroll
            for (int dt = 0; dt < 4; ++dt) {
                bf16x4_t w2 = *reinterpret_cast<const bf16x4_t*>(
                    W2l + (((hw * 2 + ht) * 4 + dt) << 8) + l * 4);
#pragma unroll
                for (int jf = 0; jf < 4; ++jf)
                    acc2[dt][jf] = __builtin_amdgcn_mfma_f32_16x16x16bf16_1k(w2, hl[jf], acc2[dt][jf], 0, 0, 0);
            }
        }
        // ---- restage F for a+1 (single buffer, 2 barriers) ----
        if (ai < 7) {
            __syncthreads();  // all F reads done
#pragma unroll
            for (int i = 0; i < 4; ++i)
                *reinterpret_cast<uint4*>(&Fbuf[fw + i * 8]) =
                    make_uint4(pack2(s[2 * i].x, s[2 * i].y), pack2(s[2 * i].z, s[2 * i].w),
                               pack2(s[2 * i + 1].x, s[2 * i + 1].y), pack2(s[2 * i + 1].z, s[2 * i + 1].w));
            if (ai < 6) {
                const float* p = sb + (size_t)(a0 + ai + 2) * 65536 + soff;
#pragma unroll
                for (int i = 0; i < 8; ++i) s[i] = *reinterpret_cast<const float4*>(p + i * 4);
            }
            __syncthreads();  // F(a+1) ready
        }
    }

    // ---- fold hw-partials via dead F buffer ([64 j][68 d] f32) ----
    float* R = reinterpret_cast<float*>(Fbuf);
#define STORE_R()                                                              \
    do {                                                                       \
        _Pragma("unroll") for (int dt = 0; dt < 4; ++dt)                       \
            _Pragma("unroll") for (int jf = 0; jf < 4; ++jf)                   \
                *reinterpret_cast<f32x4_t*>(                                   \
                    &R[(jf * 16 + lm) * 68 + dt * 16 + lk * 4]) = acc2[dt][jf];\
    } while (0)
#define ADD_R()                                                                \
    do {                                                                       \
        _Pragma("unroll") for (int dt = 0; dt < 4; ++dt)                       \
            _Pragma("unroll") for (int jf = 0; jf < 4; ++jf)                   \
                acc2[dt][jf] += *reinterpret_cast<const f32x4_t*>(             \
                    &R[(jf * 16 + lm) * 68 + dt * 16 + lk * 4]);               \
    } while (0)
    __syncthreads();
    if (hw == 1) STORE_R();
    __syncthreads();
    if (hw == 0) ADD_R();
    __syncthreads();
    if (hw == 3) STORE_R();
    __syncthreads();
    if (hw == 2) ADD_R();
    __syncthreads();
    if (hw == 2) STORE_R();
    __syncthreads();
    if (hw == 0) {
        ADD_R();
#pragma unroll
        for (int dt = 0; dt < 4; ++dt)
#pragma unroll
            for (int jf = 0; jf < 4; ++jf)
                *reinterpret_cast<float4*>(
                    &partial[(size_t)(hh * 16 + ac) * 65536 +
                             (j0 + jf * 16 + lm) * 64 + dt * 16 + lk * 4]) =
                    *reinterpret_cast<float4*>(&acc2[dt][jf]);
    }
#undef STORE_R
#undef ADD_R
}

// ---------------------------------------------------------------------------
// Kernel C: fused d-link MLP + per-AP normalization. One block per AP,
// 512 threads. Folds the 32-chunk partial reduction for its 8 ue rows.
// ---------------------------------------------------------------------------
__global__ __launch_bounds__(512) void dlink_norm(
        const float* __restrict__ pv_re, const float* __restrict__ pv_im,
        const float* __restrict__ pldre, const float* __restrict__ pldim,
        const float* __restrict__ partial, const float* __restrict__ b2b,
        const float* __restrict__ W1aT, const float* __restrict__ b1a,
        const float* __restrict__ W1bT, const float* __restrict__ b1b,
        float* __restrict__ Q, float* __restrict__ out) {
    int a = blockIdx.x, t = threadIdx.x, w = t >> 6, l = t & 63;
    __shared__ float pvr[512], pvi[512], pldr[512], pldi[512];
    __shared__ float nrm[8][8];
    __shared__ __attribute__((aligned(16))) float feat[8][212];
    __shared__ __attribute__((aligned(16))) float h1[8][260];
    __shared__ float red2[2][8][128];
    __shared__ __attribute__((aligned(16))) float o1[8][128];
    __shared__ float redn[8];
    __shared__ float SshInv;

    pvr[t] = pv_re[a * 512 + t];
    pvi[t] = pv_im[a * 512 + t];
    pldr[t] = pldre[a * 512 + t];
    pldi[t] = pldim[a * 512 + t];
    {
        float acc = 128.f * b2b[t & 63];
#pragma unroll
        for (int c = 0; c < 32; ++c) acc += partial[c * 65536 + a * 512 + t];
        feat[t >> 6][129 + (t & 63)] = acc;
    }
    if (t < 152) feat[t / 19][193 + t % 19] = 0.f;
    __syncthreads();
    feat[t >> 6][1 + (t & 63)] = pldr[t];
    feat[t >> 6][65 + (t & 63)] = pldi[t];
#pragma unroll
    for (int p = 0; p < 8; ++p) {
        int idx = w * 8 + p;
        int el = idx >> 3, u = idx & 7;
        float pr = pvr[u * 64 + l], pi = pvi[u * 64 + l];
        float qr = pldr[el * 64 + l], qi = pldi[el * 64 + l];
        float ir = pr * qr + pi * qi;
        float ii = pr * qi - pi * qr;
        for (int m = 1; m < 64; m <<= 1) {
            ir += __shfl_xor(ir, m, 64);
            ii += __shfl_xor(ii, m, 64);
        }
        if (l == 0) nrm[el][u] = ir * ir + ii * ii;
    }
    __syncthreads();
    if (t < 8) {
        float s = 0.f;
        for (int u = 0; u < 8; ++u)
            if (u != t) s += nrm[t][u];
        feat[t][0] = s;
    }
    __syncthreads();
    {
        int h = t >> 1, e0 = (t & 1) * 4;
        const float4* wrow = reinterpret_cast<const float4*>(W1aT + h * 208);
        const float4* f0p = reinterpret_cast<const float4*>(&feat[e0 + 0][0]);
        const float4* f1p = reinterpret_cast<const float4*>(&feat[e0 + 1][0]);
        const float4* f2p = reinterpret_cast<const float4*>(&feat[e0 + 2][0]);
        const float4* f3p = reinterpret_cast<const float4*>(&feat[e0 + 3][0]);
        float ac0 = 0.f, ac1 = 0.f, ac2 = 0.f, ac3 = 0.f;
#pragma unroll 4
        for (int kq = 0; kq < 52; ++kq) {
            float4 wv = wrow[kq];
            float4 f0 = f0p[kq], f1 = f1p[kq], f2 = f2p[kq], f3 = f3p[kq];
            ac0 = fmaf(wv.x, f0.x, ac0); ac0 = fmaf(wv.y, f0.y, ac0);
            ac0 = fmaf(wv.z, f0.z, ac0); ac0 = fmaf(wv.w, f0.w, ac0);
            ac1 = fmaf(wv.x, f1.x, ac1); ac1 = fmaf(wv.y, f1.y, ac1);
            ac1 = fmaf(wv.z, f1.z, ac1); ac1 = fmaf(wv.w, f1.w, ac1);
            ac2 = fmaf(wv.x, f2.x, ac2); ac2 = fmaf(wv.y, f2.y, ac2);
            ac2 = fmaf(wv.z, f2.z, ac2); ac2 = fmaf(wv.w, f2.w, ac2);
            ac3 = fmaf(wv.x, f3.x, ac3); ac3 = fmaf(wv.y, f3.y, ac3);
            ac3 = fmaf(wv.z, f3.z, ac3); ac3 = fmaf(wv.w, f3.w, ac3);
        }
        float bb = b1a[h];
        float s0 = bb + ac0, s1 = bb + ac1, s2 = bb + ac2, s3 = bb + ac3;
        h1[e0 + 0][h] = s0 > 0.f ? s0 : 0.f;
        h1[e0 + 1][h] = s1 > 0.f ? s1 : 0.f;
        h1[e0 + 2][h] = s2 > 0.f ? s2 : 0.f;
        h1[e0 + 3][h] = s3 > 0.f ? s3 : 0.f;
    }
    __syncthreads();
    {
        int e0 = (t & 1) * 4, c = (t >> 1) & 127, kh = t >> 8;
        const float4* wrow = reinterpret_cast<const float4*>(W1bT + c * 256 + kh * 128);
        const float4* g0 = reinterpret_cast<const float4*>(&h1[e0 + 0][kh * 128]);
        const float4* g1 = reinterpret_cast<const float4*>(&h1[e0 + 1][kh * 128]);
        const float4* g2 = reinterpret_cast<const float4*>(&h1[e0 + 2][kh * 128]);
        const float4* g3 = reinterpret_cast<const float4*>(&h1[e0 + 3][kh * 128]);
        float ac0 = 0.f, ac1 = 0.f, ac2 = 0.f, ac3 = 0.f;
#pragma unroll 4
        for (int kq = 0; kq < 32; ++kq) {
            float4 wv = wrow[kq];
            float4 f0 = g0[kq], f1 = g1[kq], f2 = g2[kq], f3 = g3[kq];
            ac0 = fmaf(wv.x, f0.x, ac0); ac0 = fmaf(wv.y, f0.y, ac0);
            ac0 = fmaf(wv.z, f0.z, ac0); ac0 = fmaf(wv.w, f0.w, ac0);
            ac1 = fmaf(wv.x, f1.x, ac1); ac1 = fmaf(wv.y, f1.y, ac1);
            ac1 = fmaf(wv.z, f1.z, ac1); ac1 = fmaf(wv.w, f1.w, ac1);
            ac2 = fmaf(wv.x, f2.x, ac2); ac2 = fmaf(wv.y, f2.y, ac2);
            ac2 = fmaf(wv.z, f2.z, ac2); ac2 = fmaf(wv.w, f2.w, ac2);
            ac3 = fmaf(wv.x, f3.x, ac3); ac3 = fmaf(wv.y, f3.y, ac3);
            ac3 = fmaf(wv.z, f3.z, ac3); ac3 = fmaf(wv.w, f3.w, ac3);
        }
        red2[kh][e0 + 0][c] = ac0;
        red2[kh][e0 + 1][c] = ac1;
        red2[kh][e0 + 2][c] = ac2;
        red2[kh][e0 + 3][c] = ac3;
    }
    __syncthreads();
    {
        int i0 = t, i1 = t + 512;
        o1[i0 >> 7][i0 & 127] = b1b[i0 & 127] + red2[0][i0 >> 7][i0 & 127] + red2[1][i0 >> 7][i0 & 127];
        o1[i1 >> 7][i1 & 127] = b1b[i1 & 127] + red2[0][i1 >> 7][i1 & 127] + red2[1][i1 >> 7][i1 & 127];
    }
    __syncthreads();
    {
        int el = t >> 6, ant = t & 63;
        float re = o1[el][ant], im = o1[el][64 + ant];
        float v = sqrtf(re * re + im * im);
        for (int m = 1; m < 64; m <<= 1) v += __shfl_xor(v, m, 64);
        if (l == 0) redn[w] = v;
    }
    __syncthreads();
    if (t == 0) {
        float S = redn[0] + redn[1] + redn[2] + redn[3] +
                  redn[4] + redn[5] + redn[6] + redn[7];
        SshInv = 1.f / S;
    }
    __syncthreads();
    {
        float inv = SshInv;
        int el = t >> 6, ant = t & 63;
        out[a * 512 + t] = o1[el][ant] * inv;
        out[65536 + a * 512 + t] = o1[el][64 + ant] * inv;
        if (t < 64) {
            float sr = 0.f, si = 0.f;
#pragma unroll
            for (int u = 0; u < 8; ++u) {
                sr += o1[u][t];
                si += o1[u][64 + t];
            }
            sr *= inv;
            si *= inv;
            Q[a * 64 + t] = sr * sr + si * si;
        }
    }
}

// ---------------------------------------------------------------------------
// Kernel D: final aggregate from fp16 P (16.8 MB). One wave per j.
// ---------------------------------------------------------------------------
__global__ __launch_bounds__(256) void final_agg(const unsigned short* __restrict__ Pws,
                                                 const float* __restrict__ Qv,
                                                 float* __restrict__ out) {
    int bid = blockIdx.x, t = threadIdx.x, w = t >> 6, l = t & 63;
    __shared__ __attribute__((aligned(16))) float Qc[128][68];
    for (int i = t; i < 8192; i += 256) Qc[i >> 6][i & 63] = Qv[i];
    __syncthreads();
    int j = bid * 4 + w;
    int as = l >> 3, og = l & 7;
    float acc = 0.f;
#pragma unroll 4
    for (int ab = 0; ab < 16; ++ab) {
        int aa = ab * 8 + as;
        uint4 pv4 = *reinterpret_cast<const uint4*>(&Pws[(unsigned)(aa * 1024 + j) * 64 + og * 8]);
        float4 q0 = *reinterpret_cast<const float4*>(&Qc[aa][og * 8]);
        float4 q1 = *reinterpret_cast<const float4*>(&Qc[aa][og * 8 + 4]);
        const unsigned short* hp = (const unsigned short*)&pv4;
        acc += __half2float(__ushort_as_half(hp[0])) * q0.x;
        acc += __half2float(__ushort_as_half(hp[1])) * q0.y;
        acc += __half2float(__ushort_as_half(hp[2])) * q0.z;
        acc += __half2float(__ushort_as_half(hp[3])) * q0.w;
        acc += __half2float(__ushort_as_half(hp[4])) * q1.x;
        acc += __half2float(__ushort_as_half(hp[5])) * q1.y;
        acc += __half2float(__ushort_as_half(hp[6])) * q1.z;
        acc += __half2float(__ushort_as_half(hp[7])) * q1.w;
    }
    for (int m = 1; m < 64; m <<= 1) acc += __shfl_xor(acc, m, 64);
    if (l == 0) out[131072 + j] = acc;
}

extern "C" void kernel_launch(void* const* d_in, const int* in_sizes, int n_in,
                              void* d_out, int out_size, void* d_ws, size_t ws_size,
                              hipStream_t stream) {
    const float* plre = (const float*)d_in[0];
    const float* plim = (const float*)d_in[1];
    const float* pldre = (const float*)d_in[2];
    const float* pldim = (const float*)d_in[3];
    const float* pvre = (const float*)d_in[4];
    const float* pvim = (const float*)d_in[5];
    const float* W2a = (const float*)d_in[6];
    const float* b2a = (const float*)d_in[7];
    const float* W2b = (const float*)d_in[8];
    const float* b2b = (const float*)d_in[9];
    const float* W1a = (const float*)d_in[10];
    const float* b1a = (const float*)d_in[11];
    const float* W1b = (const float*)d_in[12];
    const float* b1b = (const float*)d_in[13];

    char* ws = (char*)d_ws;
    float* Sa = (float*)(ws);                               // 131072 B
    unsigned short* WpF = (unsigned short*)(ws + 131072);   // 65536 B
    unsigned short* W2F = (unsigned short*)(ws + 196608);   // 32768 B
    float* Q = (float*)(ws + 229376);                       // 32768 B
    float* W1aT = (float*)(ws + 262144);                    // 212992 B
    float* W1bT = (float*)(ws + 475136);                    // 131072 B
    float* partial = (float*)(ws + 606208);                 // 8388608 B (32 chunks)
    unsigned short* Pws = (unsigned short*)(ws + 8994816);  // 16777216 B
    float* out = (float*)d_out;

    prep_kernel<<<168, 256, 0, stream>>>(pvre, pvim, W2a, b2a, W2b, W1a, W1b,
                                         Sa, WpF, W2F, W1aT, W1bT);
    mlp2_kernel<<<512, 256, 0, stream>>>(plre, plim, Sa, WpF, W2F, partial, Pws);
    dlink_norm<<<128, 512, 0, stream>>>(pvre, pvim, pldre, pldim, partial, b2b,
                                        W1aT, b1a, W1bT, b1b, Q, out);
    final_agg<<<256, 256, 0, stream>>>(Pws, Q, out);
}